// Round 4
// baseline (1866.238 us; speedup 1.0000x reference)
//
#include <hip/hip_runtime.h>
#include <hip/hip_bf16.h>

#define PTS 8192
#define NSPLIT 8

// ---------------- top-16 (smallest) maintenance, fully static indexing ----------------
__device__ __forceinline__ void top_init(float (&bd)[16], int (&bi)[16]) {
#pragma unroll
  for (int t = 0; t < 16; ++t) { bd[t] = 3e38f; bi[t] = 0; }
}

// sorted ascending; bd[15] is current worst
__device__ __forceinline__ void top_insert(float (&bd)[16], int (&bi)[16], float d, int j) {
  if (d < bd[15]) {
#pragma unroll
    for (int t = 15; t >= 0; --t) {
      bool c  = d < bd[t];
      bool cp = (t > 0) ? (d < bd[t - 1]) : false;
      float nd = cp ? bd[t - 1] : d;
      int   ni = cp ? bi[t - 1] : j;
      if (c) { bd[t] = nd; bi[t] = ni; }
    }
  }
}

// ---------------- squared norms ----------------
__global__ void sqnorm_kernel(const float* __restrict__ h, float* __restrict__ sq, int C) {
  int i = blockIdx.x * 256 + threadIdx.x;
  if (i >= PTS) return;
  const float* r = h + (size_t)i * C;
  float s = 0.f;
  if ((C & 3) == 0) {
    for (int k = 0; k < C; k += 4) {
      float4 v = *(const float4*)(r + k);
      s += v.x * v.x + v.y * v.y + v.z * v.z + v.w * v.w;
    }
  } else {
    for (int k = 0; k < C; ++k) s += r[k] * r[k];
  }
  sq[i] = s;
}

// ---------------- fused pairwise-distance + per-row top-16 ----------------
// grid = 1024 blocks (1D). slice = b&7 (XCD-affine), row-tile = b>>3.
// A-tile (64 x C) resident in LDS; B double-buffered per 32-k chunk.
// LDS XOR-swizzle (word ^= (k&7)<<2) instead of padding: total exactly 64 KB at C=128.
template <int C>
__global__ __launch_bounds__(256, 4) void knn_kernel(const float* __restrict__ H,
                                                     const float* __restrict__ sq,
                                                     float* __restrict__ pd,
                                                     int* __restrict__ pi) {
  constexpr int KC = (C < 32) ? C : 32;      // k-chunk
  constexpr int NC = C / KC;                 // chunks per tile: 1,2,4
  constexpr int TT = (PTS / NSPLIT) / 64;    // 16 column tiles per block
  constexpr int N  = TT * NC;                // total chunks

  __shared__ float AsF[C * 64];              // [k][row], swizzled
  __shared__ float BsF[2 * 32 * 64];         // dbuf [k][col], swizzled
  __shared__ float D2F[64 * 64];             // [row][col], swizzled

  const int tid  = threadIdx.x;
  const int b    = blockIdx.x;
  const int sy   = b & 7;                    // candidate slice (XCD-affine)
  const int sx   = b >> 3;                   // row tile
  const int row0 = sx * 64;
  const int cb   = sy * (PTS / NSPLIT);
  const int tx = tid & 15, ty = tid >> 4;
  const int r_ = tid & 63, p_ = tid >> 6;

  // ---- stage A (C x 64) once ----
  if constexpr (C >= 32) {
    const int kq = tid & 7, rr0 = tid >> 3;  // rr0 in 0..31
#pragma unroll
    for (int kc = 0; kc < C; kc += 32) {
#pragma unroll
      for (int l = 0; l < 2; ++l) {
        int rr = rr0 + l * 32;
        float4 v = *(const float4*)(H + (size_t)(row0 + rr) * C + kc + kq * 4);
        float vv[4] = {v.x, v.y, v.z, v.w};
#pragma unroll
        for (int j = 0; j < 4; ++j) {
          int k = kc + kq * 4 + j;
          AsF[k * 64 + (rr ^ ((k & 7) << 2))] = vv[j];
        }
      }
    }
  } else {
    const int kk = tid & 3, rr = tid >> 2;   // rr 0..63
    if (kk < C) AsF[kk * 64 + (rr ^ ((kk & 7) << 2))] = H[(size_t)(row0 + rr) * C + kk];
  }

  float sqr[4];
#pragma unroll
  for (int u = 0; u < 4; ++u) sqr[u] = sq[row0 + ty * 4 + u];

  float bd[16]; int bi[16];
  top_init(bd, bi);

  float st[8];
  auto stage_load = [&](int n1) {
    if constexpr (C >= 32) {
      const int kq = tid & 7, cc0 = tid >> 3;
      int ct1 = (n1 / NC) * 64, kc1 = (n1 % NC) * 32;
#pragma unroll
      for (int l = 0; l < 2; ++l) {
        float4 v = *(const float4*)(H + (size_t)(cb + ct1 + cc0 + l * 32) * C + kc1 + kq * 4);
        st[l * 4 + 0] = v.x; st[l * 4 + 1] = v.y; st[l * 4 + 2] = v.z; st[l * 4 + 3] = v.w;
      }
    } else {
      const int kk = tid & 3, cc = tid >> 2;
      if (kk < C) st[0] = H[(size_t)(cb + n1 * 64 + cc) * C + kk];
    }
  };
  auto stage_write = [&](int n1) {
    float* B = BsF + (n1 & 1) * (32 * 64);
    if constexpr (C >= 32) {
      const int kq = tid & 7, cc0 = tid >> 3;
#pragma unroll
      for (int l = 0; l < 2; ++l)
#pragma unroll
        for (int j = 0; j < 4; ++j) {
          int k = kq * 4 + j;
          B[k * 64 + ((cc0 + l * 32) ^ ((k & 7) << 2))] = st[l * 4 + j];
        }
    } else {
      const int kk = tid & 3, cc = tid >> 2;
      if (kk < C) B[kk * 64 + (cc ^ ((kk & 7) << 2))] = st[0];
    }
  };

  // ---- prologue: stage chunk 0 ----
  stage_load(0);
  stage_write(0);
  __syncthreads();

  float acc[4][4] = {};
  for (int n = 0; n < N; ++n) {
    const int p = n & 1;
    const bool hasNext = (n + 1 < N);
    if (hasNext) stage_load(n + 1);

    const bool boundary = ((n % NC) == NC - 1);
    const int ct = (n / NC) * 64;
    float sqc[4];
    if (boundary) {
#pragma unroll
      for (int v = 0; v < 4; ++v) sqc[v] = sq[cb + ct + tx * 4 + v];
    }

    const float* Bp = BsF + p * (32 * 64);
    const int kc = (n % NC) * 32;
#pragma unroll
    for (int k = 0; k < KC; ++k) {
      const int sw = (k & 7) << 2;
      float4 a4 = *(const float4*)(AsF + (kc + k) * 64 + ((ty * 4) ^ sw));
      float4 b4 = *(const float4*)(Bp + k * 64 + ((tx * 4) ^ sw));
      float a[4]  = {a4.x, a4.y, a4.z, a4.w};
      float bb[4] = {b4.x, b4.y, b4.z, b4.w};
#pragma unroll
      for (int u = 0; u < 4; ++u)
#pragma unroll
        for (int v = 0; v < 4; ++v)
          acc[u][v] += a[u] * bb[v];
    }
    if (hasNext) stage_write(n + 1);
    __syncthreads();

    if (boundary) {
#pragma unroll
      for (int u = 0; u < 4; ++u) {
        int row = ty * 4 + u;
        int gr  = row0 + row;
        float dv[4];
#pragma unroll
        for (int v = 0; v < 4; ++v) {
          float d2 = sqr[u] + sqc[v] - 2.f * acc[u][v];
          if (gr == cb + ct + tx * 4 + v) d2 = 3e38f;  // exclude self
          dv[v] = d2;
          acc[u][v] = 0.f;
        }
        *(float4*)(D2F + row * 64 + ((tx * 4) ^ ((row & 7) << 2))) =
            make_float4(dv[0], dv[1], dv[2], dv[3]);
      }
      __syncthreads();
#pragma unroll
      for (int q = 0; q < 16; ++q) {
        int cc = p_ * 16 + ((q + r_) & 15);  // rotation de-correlates banks
        float d = D2F[r_ * 64 + (cc ^ ((r_ & 7) << 2))];
        top_insert(bd, bi, d, cb + ct + cc);
      }
      // no barrier needed: next chunk's barrier orders D2 reuse
    }
  }

  // ---- in-block merge of the 4 per-wave lists (wave 0 merges) ----
  __syncthreads();
  if (p_ > 0) {
    int* iTmp = (int*)BsF;  // Bs dead; 3072 ints fit in 2*32*64
#pragma unroll
    for (int t = 0; t < 16; ++t) {
      int c2 = p_ * 16 + t;
      D2F[r_ * 64 + (c2 ^ ((r_ & 7) << 2))] = bd[t];
      iTmp[r_ * 48 + (p_ - 1) * 16 + t] = bi[t];
    }
  }
  __syncthreads();
  if (p_ == 0) {
    const int* iTmp = (const int*)BsF;
    for (int L = 1; L < 4; ++L) {
      for (int t = 0; t < 16; ++t) {
        int c2 = L * 16 + t;
        float d = D2F[r_ * 64 + (c2 ^ ((r_ & 7) << 2))];
        if (d >= bd[15]) break;  // lists sorted ascending
        top_insert(bd, bi, d, iTmp[r_ * 48 + (L - 1) * 16 + t]);
      }
    }
    size_t base = ((size_t)(row0 + r_) * NSPLIT + sy) * 16;
#pragma unroll
    for (int t = 0; t < 16; ++t) { pd[base + t] = bd[t]; pi[base + t] = bi[t]; }
  }
}

__global__ void knn_merge_kernel(const float* __restrict__ pd, const int* __restrict__ pi,
                                 int* __restrict__ idx) {
  int i = blockIdx.x * 256 + threadIdx.x;
  if (i >= PTS) return;
  float bd[16]; int bi[16];
  top_init(bd, bi);
  const float* d  = pd + (size_t)i * (NSPLIT * 16);
  const int*   ii = pi + (size_t)i * (NSPLIT * 16);
  for (int L = 0; L < NSPLIT; ++L) {
    for (int t = 0; t < 16; ++t) {
      float dv = d[L * 16 + t];
      if (dv >= bd[15]) break;              // sorted sublists
      top_insert(bd, bi, dv, ii[L * 16 + t]);
    }
  }
#pragma unroll
  for (int t = 0; t < 16; ++t) idx[(size_t)i * 16 + t] = bi[t];
}

// ---------------- tiled f32 GEMM computing F = A@Wt + bias (z=0) and G = A@Wb (z=1) ----------------
__global__ __launch_bounds__(256) void gemm_fg_kernel(const float* __restrict__ A,
                                                      const float* __restrict__ Wt,
                                                      const float* __restrict__ Wb,
                                                      const float* __restrict__ bias,
                                                      float* __restrict__ F, float* __restrict__ G,
                                                      int K, int N) {
  __shared__ float As[16][68];
  __shared__ float Bs[16][68];
  const int tid  = threadIdx.x;
  const int row0 = blockIdx.x * 64, col0 = blockIdx.y * 64;
  const float* B = (blockIdx.z == 0) ? Wt : Wb;
  float* O       = (blockIdx.z == 0) ? F  : G;
  const int tx = tid & 15, ty = tid >> 4;
  float acc[4][4] = {};
  for (int k0 = 0; k0 < K; k0 += 16) {
    __syncthreads();
#pragma unroll
    for (int l = 0; l < 4; ++l) {
      int rr = (tid >> 4) + l * 16, kk = tid & 15;
      As[kk][rr] = (k0 + kk < K) ? A[(size_t)(row0 + rr) * K + k0 + kk] : 0.f;
      int cc = tid & 63, k2 = (tid >> 6) + l * 4;
      Bs[k2][cc] = (k0 + k2 < K) ? B[(size_t)(k0 + k2) * N + col0 + cc] : 0.f;
    }
    __syncthreads();
#pragma unroll
    for (int k = 0; k < 16; ++k) {
      float4 a4 = *(const float4*)&As[k][ty * 4];
      float4 b4 = *(const float4*)&Bs[k][tx * 4];
      float a[4] = {a4.x, a4.y, a4.z, a4.w};
      float b[4] = {b4.x, b4.y, b4.z, b4.w};
#pragma unroll
      for (int u = 0; u < 4; ++u)
#pragma unroll
        for (int v = 0; v < 4; ++v)
          acc[u][v] += a[u] * b[v];
    }
  }
  float bv[4] = {0.f, 0.f, 0.f, 0.f};
  if (blockIdx.z == 0) {
#pragma unroll
    for (int v = 0; v < 4; ++v) bv[v] = bias[col0 + tx * 4 + v];
  }
#pragma unroll
  for (int u = 0; u < 4; ++u)
#pragma unroll
    for (int v = 0; v < 4; ++v)
      O[(size_t)(row0 + ty * 4 + u) * N + col0 + tx * 4 + v] = acc[u][v] + bv[v];
}

// ---------------- out_i = relu(F_i - G_i + max_{j in idx_i} G_j) ----------------
__global__ void gather_max_kernel(const float* __restrict__ F, const float* __restrict__ G,
                                  const int* __restrict__ idx, float* __restrict__ Ho, int Cn) {
  int t = blockIdx.x * 256 + threadIdx.x;
  int per = Cn >> 2;
  int i = t / per;
  if (i >= PTS) return;
  int c = (t - i * per) * 4;
  const int* ji = idx + (size_t)i * 16;
  float4 m = make_float4(-3e38f, -3e38f, -3e38f, -3e38f);
#pragma unroll
  for (int s = 0; s < 16; ++s) {
    float4 v = *(const float4*)(G + (size_t)ji[s] * Cn + c);
    m.x = fmaxf(m.x, v.x); m.y = fmaxf(m.y, v.y);
    m.z = fmaxf(m.z, v.z); m.w = fmaxf(m.w, v.w);
  }
  float4 gi = *(const float4*)(G + (size_t)i * Cn + c);
  float4 f  = *(const float4*)(F + (size_t)i * Cn + c);
  float4 o;
  o.x = fmaxf(f.x - gi.x + m.x, 0.f);
  o.y = fmaxf(f.y - gi.y + m.y, 0.f);
  o.z = fmaxf(f.z - gi.z + m.z, 0.f);
  o.w = fmaxf(f.w - gi.w + m.w, 0.f);
  *(float4*)(Ho + (size_t)i * Cn + c) = o;
}

// ---------------- final MLP: out = relu(h3@fW1+fb1)@fW2 + fb2 ----------------
__global__ __launch_bounds__(256) void mlp_kernel(const float* __restrict__ h3,
                                                  const float* __restrict__ fW1,
                                                  const float* __restrict__ fb1,
                                                  const float* __restrict__ fW2,
                                                  const float* __restrict__ fb2,
                                                  float* __restrict__ out) {
  __shared__ float hs[16][260];
  __shared__ float ws[64][128];
  __shared__ float red[4][8];
  const int tid = threadIdx.x;
  const int p0  = blockIdx.x * 16;
#pragma unroll
  for (int l = 0; l < 16; ++l) {
    int ii = l * 256 + tid;
    hs[ii >> 8][ii & 255] = h3[(size_t)(p0 + (ii >> 8)) * 256 + (ii & 255)];
  }
  const int c = tid & 127, half = tid >> 7;
  float acc[8];
#pragma unroll
  for (int pp = 0; pp < 8; ++pp) acc[pp] = fb1[c];
  for (int k0 = 0; k0 < 256; k0 += 64) {
    __syncthreads();
#pragma unroll
    for (int l = 0; l < 32; ++l) {
      int ii = l * 256 + tid;
      ws[ii >> 7][ii & 127] = fW1[(size_t)(k0 + (ii >> 7)) * 128 + (ii & 127)];
    }
    __syncthreads();
    for (int k = 0; k < 64; k += 4) {
      float w0 = ws[k][c], w1 = ws[k + 1][c], w2 = ws[k + 2][c], w3 = ws[k + 3][c];
#pragma unroll
      for (int pp = 0; pp < 8; ++pp) {
        float4 h4 = *(const float4*)&hs[half * 8 + pp][k0 + k];
        acc[pp] += h4.x * w0 + h4.y * w1 + h4.z * w2 + h4.w * w3;
      }
    }
  }
  float w2v = fW2[c];
  float s[8];
#pragma unroll
  for (int pp = 0; pp < 8; ++pp) s[pp] = fmaxf(acc[pp], 0.f) * w2v;
#pragma unroll
  for (int off = 32; off > 0; off >>= 1) {
#pragma unroll
    for (int pp = 0; pp < 8; ++pp) s[pp] += __shfl_down(s[pp], off);
  }
  if ((tid & 63) == 0) {
#pragma unroll
    for (int pp = 0; pp < 8; ++pp) red[tid >> 6][pp] = s[pp];
  }
  __syncthreads();
  if (tid < 16) {
    int hf = tid >> 3, pp = tid & 7;
    float v = red[hf * 2][pp] + red[hf * 2 + 1][pp] + fb2[0];
    out[p0 + hf * 8 + pp] = v;
  }
}

// ---------------- host ----------------
extern "C" void kernel_launch(void* const* d_in, const int* in_sizes, int n_in,
                              void* d_out, int out_size, void* d_ws, size_t ws_size,
                              hipStream_t stream) {
  (void)in_sizes; (void)n_in; (void)out_size; (void)ws_size;
  const float* x   = (const float*)d_in[0];
  const float* W1  = (const float*)d_in[1];
  const float* b1  = (const float*)d_in[2];
  const float* W2  = (const float*)d_in[3];
  const float* b2  = (const float*)d_in[4];
  const float* W3  = (const float*)d_in[5];
  const float* b3  = (const float*)d_in[6];
  const float* fW1 = (const float*)d_in[7];
  const float* fb1 = (const float*)d_in[8];
  const float* fW2 = (const float*)d_in[9];
  const float* fb2 = (const float*)d_in[10];

  float* w = (float*)d_ws;
  size_t o = 0;
  float* sq  = w + o; o += PTS;
  float* h1  = w + o; o += (size_t)PTS * 64;
  float* h2  = w + o; o += (size_t)PTS * 128;
  float* h3  = w + o; o += (size_t)PTS * 256;
  float* F   = w + o; o += (size_t)PTS * 256;
  float* G   = w + o; o += (size_t)PTS * 256;
  float* pd  = w + o; o += (size_t)PTS * 128;
  int*   pi  = (int*)(w + o); o += (size_t)PTS * 128;
  int*   idx = (int*)(w + o); o += (size_t)PTS * 16;

  // ---- layer 1 (C=3 -> 64) ----
  sqnorm_kernel<<<PTS / 256, 256, 0, stream>>>(x, sq, 3);
  knn_kernel<3><<<128 * NSPLIT, 256, 0, stream>>>(x, sq, pd, pi);
  knn_merge_kernel<<<PTS / 256, 256, 0, stream>>>(pd, pi, idx);
  gemm_fg_kernel<<<dim3(PTS / 64, 1, 2), 256, 0, stream>>>(x, W1, W1 + 3 * 64, b1, F, G, 3, 64);
  gather_max_kernel<<<(PTS * 16 + 255) / 256, 256, 0, stream>>>(F, G, idx, h1, 64);

  // ---- layer 2 (C=64 -> 128) ----
  sqnorm_kernel<<<PTS / 256, 256, 0, stream>>>(h1, sq, 64);
  knn_kernel<64><<<128 * NSPLIT, 256, 0, stream>>>(h1, sq, pd, pi);
  knn_merge_kernel<<<PTS / 256, 256, 0, stream>>>(pd, pi, idx);
  gemm_fg_kernel<<<dim3(PTS / 64, 2, 2), 256, 0, stream>>>(h1, W2, W2 + 64 * 128, b2, F, G, 64, 128);
  gather_max_kernel<<<(PTS * 32 + 255) / 256, 256, 0, stream>>>(F, G, idx, h2, 128);

  // ---- layer 3 (C=128 -> 256) ----
  sqnorm_kernel<<<PTS / 256, 256, 0, stream>>>(h2, sq, 128);
  knn_kernel<128><<<128 * NSPLIT, 256, 0, stream>>>(h2, sq, pd, pi);
  knn_merge_kernel<<<PTS / 256, 256, 0, stream>>>(pd, pi, idx);
  gemm_fg_kernel<<<dim3(PTS / 64, 4, 2), 256, 0, stream>>>(h2, W3, W3 + 128 * 256, b3, F, G, 128, 256);
  gather_max_kernel<<<(PTS * 64 + 255) / 256, 256, 0, stream>>>(F, G, idx, h3, 256);

  // ---- final MLP ----
  mlp_kernel<<<PTS / 16, 256, 0, stream>>>(h3, fW1, fb1, fW2, fb2, (float*)d_out);
}

// Round 5
// 1214.812 us; speedup vs baseline: 1.5362x; 1.5362x over previous
//
#include <hip/hip_runtime.h>
#include <hip/hip_bf16.h>

#define PTS 8192
#define NSPLIT 8

// ---------------- top-16 (smallest) maintenance, fully static indexing ----------------
__device__ __forceinline__ void top_init(float (&bd)[16], int (&bi)[16]) {
#pragma unroll
  for (int t = 0; t < 16; ++t) { bd[t] = 3e38f; bi[t] = 0; }
}

// sorted ascending; bd[15] is current worst
__device__ __forceinline__ void top_insert(float (&bd)[16], int (&bi)[16], float d, int j) {
  if (d < bd[15]) {
#pragma unroll
    for (int t = 15; t >= 0; --t) {
      bool c  = d < bd[t];
      bool cp = (t > 0) ? (d < bd[t - 1]) : false;
      float nd = cp ? bd[t - 1] : d;
      int   ni = cp ? bi[t - 1] : j;
      if (c) { bd[t] = nd; bi[t] = ni; }
    }
  }
}

// ---------------- squared norms ----------------
__global__ void sqnorm_kernel(const float* __restrict__ h, float* __restrict__ sq, int C) {
  int i = blockIdx.x * 256 + threadIdx.x;
  if (i >= PTS) return;
  const float* r = h + (size_t)i * C;
  float s = 0.f;
  if ((C & 3) == 0) {
    for (int k = 0; k < C; k += 4) {
      float4 v = *(const float4*)(r + k);
      s += v.x * v.x + v.y * v.y + v.z * v.z + v.w * v.w;
    }
  } else {
    for (int k = 0; k < C; ++k) s += r[k] * r[k];
  }
  sq[i] = s;
}

// ---------------- fused pairwise-distance + per-row top-16 ----------------
// grid = 2048 blocks of 128 thr (2 waves). slice = b&7 (XCD-affine), row-tile = b>>3 (32 rows).
// A-tile (32 x C) resident in LDS; B single-buffered per 32-k chunk; D2 32x64.
// LDS = 32KB @ C=128 -> 4-5 blocks/CU. XOR-swizzle (word ^= (k&7)<<2) throughout.
template <int C>
__global__ __launch_bounds__(128, 2) void knn_kernel(const float* __restrict__ H,
                                                     const float* __restrict__ sq,
                                                     float* __restrict__ pd,
                                                     int* __restrict__ pi) {
  constexpr int KC = (C < 32) ? C : 32;      // k-chunk
  constexpr int NC = C / KC;                 // chunks per tile: 1,2,4
  constexpr int TT = (PTS / NSPLIT) / 64;    // 16 column tiles per block
  constexpr int N  = TT * NC;                // total chunks

  __shared__ float AsF[C * 32];              // [k][row32], swizzled
  __shared__ float BsF[KC * 64];             // [k][col64], swizzled
  __shared__ float D2F[32 * 64];             // [row][col], swizzled

  const int tid  = threadIdx.x;
  const int b    = blockIdx.x;
  const int sy   = b & 7;                    // candidate slice (XCD-affine)
  const int sx   = b >> 3;                   // row tile
  const int row0 = sx * 32;
  const int cb   = sy * (PTS / NSPLIT);
  const int tx = tid & 15, ty = tid >> 4;    // micro-tile: 4 cols x 4 rows
  const int l_ = tid & 63, p_ = tid >> 6;    // lane, wave
  const int row_s = l_ & 31;                 // scan row
  const int h2 = (p_ << 1) | (l_ >> 5);      // col half 0..3 (16 cols each)

  // ---- stage A (C x 32) once ----
  if constexpr (C >= 32) {
    constexpr int QPR = C / 4;               // float4 quads per row
    constexpr int RP  = 128 / QPR;           // rows per pass
    const int q  = tid % QPR;
    const int r0 = tid / QPR;
#pragma unroll
    for (int l = 0; l < 32 / RP; ++l) {
      int rr = r0 + l * RP;
      float4 v = *(const float4*)(H + (size_t)(row0 + rr) * C + q * 4);
      float vv[4] = {v.x, v.y, v.z, v.w};
#pragma unroll
      for (int j = 0; j < 4; ++j) {
        int k = q * 4 + j;
        AsF[k * 32 + (rr ^ ((k & 7) << 2))] = vv[j];
      }
    }
  } else {
    if (tid < 32 * C) {
      int rr = tid & 31, kk = tid >> 5;
      AsF[kk * 32 + (rr ^ ((kk & 7) << 2))] = H[(size_t)(row0 + rr) * C + kk];
    }
  }

  float sqr[4];
#pragma unroll
  for (int u = 0; u < 4; ++u) sqr[u] = sq[row0 + ty * 4 + u];

  float bd[16]; int bi[16];
  top_init(bd, bi);

  float acc[4][4] = {};
  for (int n = 0; n < N; ++n) {
    const int ct = (n / NC) * 64;
    const int kc = (n % NC) * KC;
    __syncthreads();                         // Bs consumed / D2 scan done
    // ---- stage B chunk (KC x 64) ----
    if constexpr (C >= 32) {
      const int q = tid & 7, cc = tid >> 3;  // k-quad, col base
      float4 vv[4];
#pragma unroll
      for (int l = 0; l < 4; ++l)
        vv[l] = *(const float4*)(H + (size_t)(cb + ct + cc + l * 16) * C + kc + q * 4);
#pragma unroll
      for (int l = 0; l < 4; ++l) {
        float t4[4] = {vv[l].x, vv[l].y, vv[l].z, vv[l].w};
#pragma unroll
        for (int j = 0; j < 4; ++j) {
          int k = q * 4 + j;
          BsF[k * 64 + ((cc + l * 16) ^ ((k & 7) << 2))] = t4[j];
        }
      }
    } else {
      if (tid < 64) {
#pragma unroll
        for (int k = 0; k < C; ++k)
          BsF[k * 64 + (tid ^ ((k & 7) << 2))] = H[(size_t)(cb + ct + tid) * C + k];
      }
    }
    __syncthreads();
    // ---- compute ----
#pragma unroll
    for (int k = 0; k < KC; ++k) {
      const int sw = (k & 7) << 2;
      float4 a4 = *(const float4*)(AsF + (kc + k) * 32 + ((ty * 4) ^ sw));
      float4 b4 = *(const float4*)(BsF + k * 64 + ((tx * 4) ^ sw));
      float a[4]  = {a4.x, a4.y, a4.z, a4.w};
      float bb[4] = {b4.x, b4.y, b4.z, b4.w};
#pragma unroll
      for (int u = 0; u < 4; ++u)
#pragma unroll
        for (int v = 0; v < 4; ++v)
          acc[u][v] += a[u] * bb[v];
    }
    if ((n % NC) == NC - 1) {
      float sqc[4];
#pragma unroll
      for (int v = 0; v < 4; ++v) sqc[v] = sq[cb + ct + tx * 4 + v];
#pragma unroll
      for (int u = 0; u < 4; ++u) {
        int row = ty * 4 + u;
        int gr  = row0 + row;
        float dv[4];
#pragma unroll
        for (int v = 0; v < 4; ++v) {
          float d2 = sqr[u] + sqc[v] - 2.f * acc[u][v];
          if (gr == cb + ct + tx * 4 + v) d2 = 3e38f;  // exclude self
          dv[v] = d2;
          acc[u][v] = 0.f;
        }
        *(float4*)(D2F + row * 64 + ((tx * 4) ^ ((row & 7) << 2))) =
            make_float4(dv[0], dv[1], dv[2], dv[3]);
      }
      __syncthreads();
      // ---- scan: lane owns (row_s, 16-col half h2) ----
#pragma unroll
      for (int q = 0; q < 16; ++q) {
        int cc = h2 * 16 + ((q + row_s) & 15);  // rotation de-correlates banks
        float d = D2F[row_s * 64 + (cc ^ ((row_s & 7) << 2))];
        top_insert(bd, bi, d, cb + ct + cc);
      }
      // next iteration's barrier orders D2/Bs reuse
    }
  }

  // ---- merge 4 per-row lists: shuffle partner (lane^32) into lanes<32 ----
  for (int t = 0; t < 16; ++t) {
    float d = __shfl(bd[t], (l_ & 31) + 32);
    int   i = __shfl(bi[t], (l_ & 31) + 32);
    unsigned long long m = __ballot((l_ < 32) && (d < bd[15]));
    if (!m) break;
    if (l_ < 32) top_insert(bd, bi, d, i);
  }
  // ---- cross-wave exchange via D2F (d in slots 0..15, idx bits in 16..31, rotated) ----
  __syncthreads();
  if (p_ == 1 && l_ < 32) {
#pragma unroll
    for (int t = 0; t < 16; ++t) {
      int s = (t + row_s) & 15;
      D2F[row_s * 64 + s] = bd[t];
      ((int*)D2F)[row_s * 64 + 16 + s] = bi[t];
    }
  }
  __syncthreads();
  if (p_ == 0 && l_ < 32) {
    for (int t = 0; t < 16; ++t) {
      int s = (t + row_s) & 15;
      float d = D2F[row_s * 64 + s];
      if (d >= bd[15]) break;               // partner list sorted ascending
      top_insert(bd, bi, d, ((int*)D2F)[row_s * 64 + 16 + s]);
    }
    size_t base = ((size_t)(row0 + row_s) * NSPLIT + sy) * 16;
#pragma unroll
    for (int t = 0; t < 16; ++t) { pd[base + t] = bd[t]; pi[base + t] = bi[t]; }
  }
}

__global__ void knn_merge_kernel(const float* __restrict__ pd, const int* __restrict__ pi,
                                 int* __restrict__ idx) {
  int i = blockIdx.x * 256 + threadIdx.x;
  if (i >= PTS) return;
  float bd[16]; int bi[16];
  top_init(bd, bi);
  const float* d  = pd + (size_t)i * (NSPLIT * 16);
  const int*   ii = pi + (size_t)i * (NSPLIT * 16);
  for (int L = 0; L < NSPLIT; ++L) {
    for (int t = 0; t < 16; ++t) {
      float dv = d[L * 16 + t];
      if (dv >= bd[15]) break;              // sorted sublists
      top_insert(bd, bi, dv, ii[L * 16 + t]);
    }
  }
#pragma unroll
  for (int t = 0; t < 16; ++t) idx[(size_t)i * 16 + t] = bi[t];
}

// ---------------- tiled f32 GEMM computing F = A@Wt + bias (z=0) and G = A@Wb (z=1) ----------------
__global__ __launch_bounds__(256) void gemm_fg_kernel(const float* __restrict__ A,
                                                      const float* __restrict__ Wt,
                                                      const float* __restrict__ Wb,
                                                      const float* __restrict__ bias,
                                                      float* __restrict__ F, float* __restrict__ G,
                                                      int K, int N) {
  __shared__ float As[16][68];
  __shared__ float Bs[16][68];
  const int tid  = threadIdx.x;
  const int row0 = blockIdx.x * 64, col0 = blockIdx.y * 64;
  const float* B = (blockIdx.z == 0) ? Wt : Wb;
  float* O       = (blockIdx.z == 0) ? F  : G;
  const int tx = tid & 15, ty = tid >> 4;
  float acc[4][4] = {};
  for (int k0 = 0; k0 < K; k0 += 16) {
    __syncthreads();
#pragma unroll
    for (int l = 0; l < 4; ++l) {
      int rr = (tid >> 4) + l * 16, kk = tid & 15;
      As[kk][rr] = (k0 + kk < K) ? A[(size_t)(row0 + rr) * K + k0 + kk] : 0.f;
      int cc = tid & 63, k2 = (tid >> 6) + l * 4;
      Bs[k2][cc] = (k0 + k2 < K) ? B[(size_t)(k0 + k2) * N + col0 + cc] : 0.f;
    }
    __syncthreads();
#pragma unroll
    for (int k = 0; k < 16; ++k) {
      float4 a4 = *(const float4*)&As[k][ty * 4];
      float4 b4 = *(const float4*)&Bs[k][tx * 4];
      float a[4] = {a4.x, a4.y, a4.z, a4.w};
      float b[4] = {b4.x, b4.y, b4.z, b4.w};
#pragma unroll
      for (int u = 0; u < 4; ++u)
#pragma unroll
        for (int v = 0; v < 4; ++v)
          acc[u][v] += a[u] * b[v];
    }
  }
  float bv[4] = {0.f, 0.f, 0.f, 0.f};
  if (blockIdx.z == 0) {
#pragma unroll
    for (int v = 0; v < 4; ++v) bv[v] = bias[col0 + tx * 4 + v];
  }
#pragma unroll
  for (int u = 0; u < 4; ++u)
#pragma unroll
    for (int v = 0; v < 4; ++v)
      O[(size_t)(row0 + ty * 4 + u) * N + col0 + tx * 4 + v] = acc[u][v] + bv[v];
}

// ---------------- out_i = relu(F_i - G_i + max_{j in idx_i} G_j) ----------------
__global__ void gather_max_kernel(const float* __restrict__ F, const float* __restrict__ G,
                                  const int* __restrict__ idx, float* __restrict__ Ho, int Cn) {
  int t = blockIdx.x * 256 + threadIdx.x;
  int per = Cn >> 2;
  int i = t / per;
  if (i >= PTS) return;
  int c = (t - i * per) * 4;
  const int* ji = idx + (size_t)i * 16;
  float4 m = make_float4(-3e38f, -3e38f, -3e38f, -3e38f);
#pragma unroll
  for (int s = 0; s < 16; ++s) {
    float4 v = *(const float4*)(G + (size_t)ji[s] * Cn + c);
    m.x = fmaxf(m.x, v.x); m.y = fmaxf(m.y, v.y);
    m.z = fmaxf(m.z, v.z); m.w = fmaxf(m.w, v.w);
  }
  float4 gi = *(const float4*)(G + (size_t)i * Cn + c);
  float4 f  = *(const float4*)(F + (size_t)i * Cn + c);
  float4 o;
  o.x = fmaxf(f.x - gi.x + m.x, 0.f);
  o.y = fmaxf(f.y - gi.y + m.y, 0.f);
  o.z = fmaxf(f.z - gi.z + m.z, 0.f);
  o.w = fmaxf(f.w - gi.w + m.w, 0.f);
  *(float4*)(Ho + (size_t)i * Cn + c) = o;
}

// ---------------- final MLP: out = relu(h3@fW1+fb1)@fW2 + fb2 ----------------
__global__ __launch_bounds__(256) void mlp_kernel(const float* __restrict__ h3,
                                                  const float* __restrict__ fW1,
                                                  const float* __restrict__ fb1,
                                                  const float* __restrict__ fW2,
                                                  const float* __restrict__ fb2,
                                                  float* __restrict__ out) {
  __shared__ float hs[16][260];
  __shared__ float ws[64][128];
  __shared__ float red[4][8];
  const int tid = threadIdx.x;
  const int p0  = blockIdx.x * 16;
#pragma unroll
  for (int l = 0; l < 16; ++l) {
    int ii = l * 256 + tid;
    hs[ii >> 8][ii & 255] = h3[(size_t)(p0 + (ii >> 8)) * 256 + (ii & 255)];
  }
  const int c = tid & 127, half = tid >> 7;
  float acc[8];
#pragma unroll
  for (int pp = 0; pp < 8; ++pp) acc[pp] = fb1[c];
  for (int k0 = 0; k0 < 256; k0 += 64) {
    __syncthreads();
#pragma unroll
    for (int l = 0; l < 32; ++l) {
      int ii = l * 256 + tid;
      ws[ii >> 7][ii & 127] = fW1[(size_t)(k0 + (ii >> 7)) * 128 + (ii & 127)];
    }
    __syncthreads();
    for (int k = 0; k < 64; k += 4) {
      float w0 = ws[k][c], w1 = ws[k + 1][c], w2 = ws[k + 2][c], w3 = ws[k + 3][c];
#pragma unroll
      for (int pp = 0; pp < 8; ++pp) {
        float4 h4 = *(const float4*)&hs[half * 8 + pp][k0 + k];
        acc[pp] += h4.x * w0 + h4.y * w1 + h4.z * w2 + h4.w * w3;
      }
    }
  }
  float w2v = fW2[c];
  float s[8];
#pragma unroll
  for (int pp = 0; pp < 8; ++pp) s[pp] = fmaxf(acc[pp], 0.f) * w2v;
#pragma unroll
  for (int off = 32; off > 0; off >>= 1) {
#pragma unroll
    for (int pp = 0; pp < 8; ++pp) s[pp] += __shfl_down(s[pp], off);
  }
  if ((tid & 63) == 0) {
#pragma unroll
    for (int pp = 0; pp < 8; ++pp) red[tid >> 6][pp] = s[pp];
  }
  __syncthreads();
  if (tid < 16) {
    int hf = tid >> 3, pp = tid & 7;
    float v = red[hf * 2][pp] + red[hf * 2 + 1][pp] + fb2[0];
    out[p0 + hf * 8 + pp] = v;
  }
}

// ---------------- host ----------------
extern "C" void kernel_launch(void* const* d_in, const int* in_sizes, int n_in,
                              void* d_out, int out_size, void* d_ws, size_t ws_size,
                              hipStream_t stream) {
  (void)in_sizes; (void)n_in; (void)out_size; (void)ws_size;
  const float* x   = (const float*)d_in[0];
  const float* W1  = (const float*)d_in[1];
  const float* b1  = (const float*)d_in[2];
  const float* W2  = (const float*)d_in[3];
  const float* b2  = (const float*)d_in[4];
  const float* W3  = (const float*)d_in[5];
  const float* b3  = (const float*)d_in[6];
  const float* fW1 = (const float*)d_in[7];
  const float* fb1 = (const float*)d_in[8];
  const float* fW2 = (const float*)d_in[9];
  const float* fb2 = (const float*)d_in[10];

  float* w = (float*)d_ws;
  size_t o = 0;
  float* sq  = w + o; o += PTS;
  float* h1  = w + o; o += (size_t)PTS * 64;
  float* h2  = w + o; o += (size_t)PTS * 128;
  float* h3  = w + o; o += (size_t)PTS * 256;
  float* F   = w + o; o += (size_t)PTS * 256;
  float* G   = w + o; o += (size_t)PTS * 256;
  float* pd  = w + o; o += (size_t)PTS * 128;
  int*   pi  = (int*)(w + o); o += (size_t)PTS * 128;
  int*   idx = (int*)(w + o); o += (size_t)PTS * 16;

  const int KNN_GRID = (PTS / 32) * NSPLIT;  // 2048

  // ---- layer 1 (C=3 -> 64) ----
  sqnorm_kernel<<<PTS / 256, 256, 0, stream>>>(x, sq, 3);
  knn_kernel<3><<<KNN_GRID, 128, 0, stream>>>(x, sq, pd, pi);
  knn_merge_kernel<<<PTS / 256, 256, 0, stream>>>(pd, pi, idx);
  gemm_fg_kernel<<<dim3(PTS / 64, 1, 2), 256, 0, stream>>>(x, W1, W1 + 3 * 64, b1, F, G, 3, 64);
  gather_max_kernel<<<(PTS * 16 + 255) / 256, 256, 0, stream>>>(F, G, idx, h1, 64);

  // ---- layer 2 (C=64 -> 128) ----
  sqnorm_kernel<<<PTS / 256, 256, 0, stream>>>(h1, sq, 64);
  knn_kernel<64><<<KNN_GRID, 128, 0, stream>>>(h1, sq, pd, pi);
  knn_merge_kernel<<<PTS / 256, 256, 0, stream>>>(pd, pi, idx);
  gemm_fg_kernel<<<dim3(PTS / 64, 2, 2), 256, 0, stream>>>(h1, W2, W2 + 64 * 128, b2, F, G, 64, 128);
  gather_max_kernel<<<(PTS * 32 + 255) / 256, 256, 0, stream>>>(F, G, idx, h2, 128);

  // ---- layer 3 (C=128 -> 256) ----
  sqnorm_kernel<<<PTS / 256, 256, 0, stream>>>(h2, sq, 128);
  knn_kernel<128><<<KNN_GRID, 128, 0, stream>>>(h2, sq, pd, pi);
  knn_merge_kernel<<<PTS / 256, 256, 0, stream>>>(pd, pi, idx);
  gemm_fg_kernel<<<dim3(PTS / 64, 4, 2), 256, 0, stream>>>(h2, W3, W3 + 128 * 256, b3, F, G, 128, 256);
  gather_max_kernel<<<(PTS * 64 + 255) / 256, 256, 0, stream>>>(F, G, idx, h3, 256);

  // ---- final MLP ----
  mlp_kernel<<<PTS / 16, 256, 0, stream>>>(h3, fW1, fb1, fW2, fb2, (float*)d_out);
}